// Round 1
// baseline (287.818 us; speedup 1.0000x reference)
//
#include <hip/hip_runtime.h>
#include <hip/hip_bf16.h>
#include <math.h>

// Problem constants
#define BB 8
#define CC 256
#define TT 8192
#define EPSF 1e-5f

typedef short v8s __attribute__((ext_vector_type(8)));
typedef float v4f __attribute__((ext_vector_type(4)));

#define MFMA(a, b, c) __builtin_amdgcn_mfma_f32_16x16x32_bf16((a), (b), (c), 0, 0, 0)

// MFMA 16x16x32 bf16 fragment conventions (m89/m91 verified):
//   A[m][k]: m = lane&15, k = (lane>>4)*8 + j   (8 contiguous k per lane)
//   B[k][n]: n = lane&15, k = (lane>>4)*8 + j
//   C/D:     col = lane&15, row = (lane>>4)*4 + reg

// Workspace layout (float offsets); total ~37.1 MB (< the ~38 MB round-1 used OK)
#define OFF_WKV 0               // Wkv bf16 [h][type][64][256]  -> 131072 ushort
#define OFF_WPJ 65536           // Wproj bf16 [256][256]        -> 65536 ushort
#define OFF_UPART 98304         // fp32 [512 blk][4h][64][64]   -> 8388608 floats
#define OFF_ZPART 8486912       // fp32 [512 blk][256]
#define OFF_KV 8617984          // fp32 [b][h][64 d][64 e]
#define OFF_PT 8749056          // Pt bf16 [b][c][256 c2]       -> 524288 ushort
#define OFF_MBF 9011200         // M bf16 [b][o][c]             -> 524288 ushort

__device__ __forceinline__ unsigned short f2bf(float f) {
  __hip_bfloat16 h = __float2bfloat16(f);
  return __builtin_bit_cast(unsigned short, h);
}
__device__ __forceinline__ float bf2f(unsigned short u) {
  return __bfloat162float(__builtin_bit_cast(__hip_bfloat16, u));
}
__device__ __forceinline__ unsigned int pack2(float lo, float hi) {
  return (unsigned int)f2bf(lo) | ((unsigned int)f2bf(hi) << 16);
}

// ---------------------------------------------------------------------------
// k0: pack weights to bf16. rows 0..511: Wkv[h][type][d][c]; rows 512..767: Wproj.
// ---------------------------------------------------------------------------
__global__ void k0_pack(const float* __restrict__ Wpre,
                        const float* __restrict__ Wproj,
                        float* __restrict__ ws) {
  const int r = blockIdx.x;
  const int c = threadIdx.x;
  if (r < 512) {
    const int h = r >> 7, type = (r >> 6) & 1, d = r & 63;
    const int src = h * 192 + 64 + type * 64 + d;
    ((unsigned short*)(ws + OFF_WKV))[r * 256 + c] = f2bf(Wpre[(size_t)src * 256 + c]);
  } else {
    const int rr = r - 512;
    ((unsigned short*)(ws + OFF_WPJ))[rr * 256 + c] = f2bf(Wproj[(size_t)rr * 256 + c]);
  }
}

// ---------------------------------------------------------------------------
// k1: per (b, 128-t chunk), 8 waves; wave = (head h = w>>1, type = w&1: 0=k,1=v).
// Grid = 8*64 = 512 blocks -> 2 blocks/CU resident (was 256 = 1/CU, the
// latency bottleneck). Per 64-t sub: stage x->LDS bf16 [t][c] with PACKED u32
// writes (channel pairs); MFMA k/v rows; exp in fp32; stage e/v to LDS
// [row][t] (pitch 40); MFMA U += e @ v^T over two 32-t halves.
// Unnormalized softmax (shift-invariant; k std ~0.8 so no overflow), Z summed
// separately. Partials U,Z written per block for k2 to reduce.
// ---------------------------------------------------------------------------
__global__ __launch_bounds__(512, 4) void k1_kv(const float* __restrict__ x,
                                                float* __restrict__ ws) {
  // union: xs[64][264] ushort (16896) overlaid by per-head e/v buffers
  // (4 heads x (64x40 ek + 64x40 v) = 20480 ushorts = 40 KiB)
  __shared__ unsigned short lds[20480];

  const int tid = threadIdx.x;
  const int w = tid >> 6, lane = tid & 63, q = lane >> 4, cl = lane & 15;
  const int h = w >> 1, type = w & 1;
  const int bi = blockIdx.x;
  const int b = bi >> 6, chunk = bi & 63;
  const int t0 = chunk * 128;
  const float* xb = x + (size_t)b * (CC * TT);
  const unsigned short* wkv =
      (const unsigned short*)(ws + OFF_WKV) + (size_t)((h * 2 + type) * 64) * 256;
  unsigned short* ekb = &lds[h * 5120];         // ek[64][40]
  unsigned short* vbb = &lds[h * 5120 + 2560];  // v [64][40]

  v4f Uacc[2][4];
#pragma unroll
  for (int i = 0; i < 2; ++i)
#pragma unroll
    for (int j = 0; j < 4; ++j) Uacc[i][j] = (v4f){0.f, 0.f, 0.f, 0.f};
  float zacc[4][4];
#pragma unroll
  for (int i = 0; i < 4; ++i)
#pragma unroll
    for (int j = 0; j < 4; ++j) zacc[i][j] = 0.f;

  // staging mapping: thread -> channel pair (c0, c0+1), t-quarter th (16 t)
  const int c0 = (tid & 127) * 2;
  const int th = tid >> 7;  // 0..3
  unsigned int* l32 = (unsigned int*)lds;

  for (int sub = 0; sub < 2; ++sub) {
    const int ts = t0 + sub * 64;
    // ---- stage xs[t][c] (bf16, pitch 264); packed u32 writes: lanes write
    // 4B consecutive -> conflict-free ----
    {
      const float* xpA = xb + (size_t)c0 * TT + ts + th * 16;
      const float* xpB = xpA + TT;
      const int cw = c0 >> 1;
#pragma unroll
      for (int k = 0; k < 4; ++k) {
        const float4 va = reinterpret_cast<const float4*>(xpA)[k];
        const float4 vb = reinterpret_cast<const float4*>(xpB)[k];
        const int tb = th * 16 + k * 4;
        l32[(tb + 0) * 132 + cw] = pack2(va.x, vb.x);
        l32[(tb + 1) * 132 + cw] = pack2(va.y, vb.y);
        l32[(tb + 2) * 132 + cw] = pack2(va.z, vb.z);
        l32[(tb + 3) * 132 + cw] = pack2(va.w, vb.w);
      }
    }
    __syncthreads();

    // ---- phase A: rows = this wave's 64 k- or v-rows, cols = 64 t ----
    v4f acc[4][4];
#pragma unroll
    for (int i = 0; i < 4; ++i)
#pragma unroll
      for (int j = 0; j < 4; ++j) acc[i][j] = (v4f){0.f, 0.f, 0.f, 0.f};
#pragma unroll
    for (int ks = 0; ks < 8; ++ks) {
      v8s af[4], bfu[4];
#pragma unroll
      for (int rt = 0; rt < 4; ++rt)
        af[rt] = *(const v8s*)(wkv + (size_t)(rt * 16 + cl) * 256 + ks * 32 + q * 8);
#pragma unroll
      for (int ct = 0; ct < 4; ++ct)
        bfu[ct] = *(const v8s*)&lds[(ct * 16 + cl) * 264 + ks * 32 + q * 8];
#pragma unroll
      for (int rt = 0; rt < 4; ++rt)
#pragma unroll
        for (int ct = 0; ct < 4; ++ct)
          acc[rt][ct] = MFMA(af[rt], bfu[ct], acc[rt][ct]);
    }
    __syncthreads();  // all waves done with xs; e/v buffers overlay it

    // ---- phase B: two 32-t halves through LDS (pitch 40: 2-way max) ----
#pragma unroll
    for (int hp = 0; hp < 2; ++hp) {
      if (type == 0) {
#pragma unroll
        for (int rt = 0; rt < 4; ++rt)
#pragma unroll
          for (int cc = 0; cc < 2; ++cc) {
            const int ct = hp * 2 + cc;
#pragma unroll
            for (int reg = 0; reg < 4; ++reg) {
              const float e = __expf(acc[rt][ct][reg]);
              zacc[rt][reg] += e;
              ekb[(rt * 16 + q * 4 + reg) * 40 + cc * 16 + cl] = f2bf(e);
            }
          }
      } else {
#pragma unroll
        for (int rt = 0; rt < 4; ++rt)
#pragma unroll
          for (int cc = 0; cc < 2; ++cc) {
            const int ct = hp * 2 + cc;
#pragma unroll
            for (int reg = 0; reg < 4; ++reg)
              vbb[(rt * 16 + q * 4 + reg) * 40 + cc * 16 + cl] =
                  f2bf(acc[rt][ct][reg]);
          }
      }
      __syncthreads();  // head's wave pair exchanges e/v
      {
        const int du0 = type * 32;  // k-wave: U rows 0..31, v-wave: 32..63
        v8s afu[2], bfu[4];
#pragma unroll
        for (int ur = 0; ur < 2; ++ur)
          afu[ur] = *(const v8s*)&ekb[(du0 + ur * 16 + cl) * 40 + q * 8];
#pragma unroll
        for (int uc = 0; uc < 4; ++uc)
          bfu[uc] = *(const v8s*)&vbb[(uc * 16 + cl) * 40 + q * 8];
#pragma unroll
        for (int ur = 0; ur < 2; ++ur)
#pragma unroll
          for (int uc = 0; uc < 4; ++uc)
            Uacc[ur][uc] = MFMA(afu[ur], bfu[uc], Uacc[ur][uc]);
      }
      __syncthreads();  // half-1 / next sub will overwrite buffers
    }
  }

  // ---- Z: butterfly over the 16 col-lanes, store from cl==0 ----
  if (type == 0) {
#pragma unroll
    for (int m = 1; m < 16; m <<= 1)
#pragma unroll
      for (int rt = 0; rt < 4; ++rt)
#pragma unroll
        for (int reg = 0; reg < 4; ++reg)
          zacc[rt][reg] += __shfl_xor(zacc[rt][reg], m, 64);
    if (cl == 0) {
      for (int rt = 0; rt < 4; ++rt)
        for (int reg = 0; reg < 4; ++reg)
          ws[OFF_ZPART + (size_t)bi * 256 + h * 64 + rt * 16 + q * 4 + reg] =
              zacc[rt][reg];
    }
  }
  // ---- U partial store ----
  float* Up = ws + OFF_UPART + (size_t)bi * 16384 + h * 4096;
#pragma unroll
  for (int ur = 0; ur < 2; ++ur)
#pragma unroll
    for (int uc = 0; uc < 4; ++uc)
#pragma unroll
      for (int reg = 0; reg < 4; ++reg)
        Up[(type * 32 + ur * 16 + q * 4 + reg) * 64 + uc * 16 + cl] =
            Uacc[ur][uc][reg];
}

// ---------------------------------------------------------------------------
// k2: reduce 64 partial blocks per batch; kv = U / Z[d].
// ---------------------------------------------------------------------------
__global__ void k2_reduce_kv(float* __restrict__ ws) {
  const int bi = blockIdx.x;  // 0..511
  const int bh = bi >> 4, j = bi & 15;
  const int b = bh >> 2, h = bh & 3;
  const int tid = threadIdx.x;

  __shared__ float zinv[64];
  if (tid < 64) {
    float z = 0.f;
    for (int cb = 0; cb < 64; ++cb)
      z += ws[OFF_ZPART + (size_t)(b * 64 + cb) * 256 + h * 64 + tid];
    zinv[tid] = 1.0f / z;
  }
  __syncthreads();

  const int idx = j * 256 + tid;  // 0..4095 in (b,h)
  const int d = idx >> 6;
  float s = 0.f;
  for (int cb = 0; cb < 64; ++cb)
    s += ws[OFF_UPART + (size_t)(b * 64 + cb) * 16384 + h * 4096 + idx];
  ws[OFF_KV + (size_t)(b * 4 + h) * 4096 + idx] = s * zinv[d];
}

// ---------------------------------------------------------------------------
// k3a: P^T[b][c][h*64+e] = sum_d kv[b,h,d,e] * Wq[h*192+d][c]  (bf16, transposed
// so k3b's B-frags are contiguous along c2)
// ---------------------------------------------------------------------------
__global__ void k3a_P(const float* __restrict__ Wpre, float* __restrict__ ws) {
  const int bi = blockIdx.x;  // b*256 + he
  const int b = bi >> 8, he = bi & 255;
  const int h = he >> 6, e = he & 63;
  const int c = threadIdx.x;
  const float* kvp = ws + OFF_KV + (size_t)(b * 4 + h) * 4096;
  float acc = 0.f;
#pragma unroll 8
  for (int d = 0; d < 64; ++d)
    acc += kvp[d * 64 + e] * Wpre[(size_t)(h * 192 + d) * 256 + c];
  ((unsigned short*)(ws + OFF_PT))[(size_t)b * 65536 + (size_t)c * 256 + he] =
      f2bf(acc);
}

// ---------------------------------------------------------------------------
// k3b: M[b][o][c] = scale * (Wproj @ P)  via MFMA; grid = 8b x 4 cg x 4 rg
// (was 32 blocks on 256 CUs -> 4x more parallelism; wave owns 16 rows).
// ---------------------------------------------------------------------------
__global__ __launch_bounds__(256, 2) void k3b_M(const float* __restrict__ scale,
                                                float* __restrict__ ws) {
  const int bi = blockIdx.x;
  const int b = bi >> 4, cg = (bi >> 2) & 3, rg = bi & 3;
  const int tid = threadIdx.x, w = tid >> 6, lane = tid & 63, q = lane >> 4,
            cl = lane & 15;
  const unsigned short* wpj = (const unsigned short*)(ws + OFF_WPJ);
  const unsigned short* pt =
      (const unsigned short*)(ws + OFF_PT) + (size_t)b * 65536;
  v4f acc[4];
#pragma unroll
  for (int j = 0; j < 4; ++j) acc[j] = (v4f){0.f, 0.f, 0.f, 0.f};
#pragma unroll
  for (int ks = 0; ks < 8; ++ks) {
    const v8s af = *(const v8s*)(wpj + (size_t)(rg * 64 + w * 16 + cl) * 256 +
                                 ks * 32 + q * 8);
    v8s bfu[4];
#pragma unroll
    for (int ct = 0; ct < 4; ++ct)
      bfu[ct] = *(const v8s*)(pt + (size_t)(cg * 64 + ct * 16 + cl) * 256 +
                              ks * 32 + q * 8);
#pragma unroll
    for (int ct = 0; ct < 4; ++ct) acc[ct] = MFMA(af, bfu[ct], acc[ct]);
  }
  const float s = scale[0];
  unsigned short* mbf = (unsigned short*)(ws + OFF_MBF);
#pragma unroll
  for (int ct = 0; ct < 4; ++ct)
#pragma unroll
    for (int reg = 0; reg < 4; ++reg) {
      const int o = rg * 64 + w * 16 + q * 4 + reg;
      const int c = cg * 64 + ct * 16 + cl;
      mbf[((size_t)b * 256 + o) * 256 + c] = f2bf(s * acc[ct][reg]);
    }
}

// ---------------------------------------------------------------------------
// k4: out = LN_C( M@x + scale*b_proj + x ) * gamma + beta, MFMA + fused LN.
// Grid: 8b x 256 chunks of 32 t; 4 waves, wave w = rows w*64..w*64+63.
// (32-t tiles: acc[4][2], ~18 KB LDS, launch_bounds(256,4) -> 4 blocks/CU.)
// ---------------------------------------------------------------------------
__global__ __launch_bounds__(256, 4) void k4_proj_ln(
    const float* __restrict__ x, const float* __restrict__ bproj,
    const float* __restrict__ scale, const float* __restrict__ gamma,
    const float* __restrict__ beta, const float* __restrict__ ws,
    float* __restrict__ out) {
  __shared__ unsigned short xs[32 * 264];
  __shared__ float red1[128], red2[128], muA[32], rsA[32];
  const int bi = blockIdx.x, b = bi >> 8, tc = bi & 255;
  const int tg0 = tc * 32;
  const int tid = threadIdx.x, w = tid >> 6, lane = tid & 63, q = lane >> 4,
            cl = lane & 15;
  const float* xb = x + (size_t)b * (CC * TT);

  // stage x[c][tg0..+32) -> xs[t][c] bf16, packed u32 channel-pair writes
  {
    const int c0 = (tid & 127) * 2;
    const int th = tid >> 7;  // 0..1
    const float* xpA = xb + (size_t)c0 * TT + tg0 + th * 16;
    const float* xpB = xpA + TT;
    unsigned int* x32 = (unsigned int*)xs;
    const int cw = c0 >> 1;
#pragma unroll
    for (int k = 0; k < 4; ++k) {
      const float4 va = reinterpret_cast<const float4*>(xpA)[k];
      const float4 vb = reinterpret_cast<const float4*>(xpB)[k];
      const int tb = th * 16 + k * 4;
      x32[(tb + 0) * 132 + cw] = pack2(va.x, vb.x);
      x32[(tb + 1) * 132 + cw] = pack2(va.y, vb.y);
      x32[(tb + 2) * 132 + cw] = pack2(va.z, vb.z);
      x32[(tb + 3) * 132 + cw] = pack2(va.w, vb.w);
    }
  }
  __syncthreads();

  const unsigned short* mbf =
      (const unsigned short*)(ws + OFF_MBF) + (size_t)b * 65536;
  v4f acc[4][2];
#pragma unroll
  for (int i = 0; i < 4; ++i)
#pragma unroll
    for (int j = 0; j < 2; ++j) acc[i][j] = (v4f){0.f, 0.f, 0.f, 0.f};
#pragma unroll
  for (int ks = 0; ks < 8; ++ks) {
    v8s af[4], bfu[2];
#pragma unroll
    for (int rt = 0; rt < 4; ++rt)
      af[rt] = *(const v8s*)(mbf + (size_t)(w * 64 + rt * 16 + cl) * 256 +
                             ks * 32 + q * 8);
#pragma unroll
    for (int ct = 0; ct < 2; ++ct)
      bfu[ct] = *(const v8s*)&xs[(ct * 16 + cl) * 264 + ks * 32 + q * 8];
#pragma unroll
    for (int rt = 0; rt < 4; ++rt)
#pragma unroll
      for (int ct = 0; ct < 2; ++ct)
        acc[rt][ct] = MFMA(af[rt], bfu[ct], acc[rt][ct]);
  }

  // y = ctx_proj + scale*b_proj + residual (residual from bf16 xs)
  const float s = scale[0];
#pragma unroll
  for (int rt = 0; rt < 4; ++rt)
#pragma unroll
    for (int reg = 0; reg < 4; ++reg) {
      const int o = w * 64 + rt * 16 + q * 4 + reg;
      const float sb = s * bproj[o];
#pragma unroll
      for (int ct = 0; ct < 2; ++ct) {
        const int tl = ct * 16 + cl;
        acc[rt][ct][reg] += sb + bf2f(xs[tl * 264 + o]);
      }
    }

  // LN sums over C: per-lane 16 rows -> butterfly over q -> cross-wave LDS
#pragma unroll
  for (int ct = 0; ct < 2; ++ct) {
    float s1 = 0.f, s2 = 0.f;
#pragma unroll
    for (int rt = 0; rt < 4; ++rt)
#pragma unroll
      for (int reg = 0; reg < 4; ++reg) {
        const float v = acc[rt][ct][reg];
        s1 += v;
        s2 += v * v;
      }
    s1 += __shfl_xor(s1, 16, 64);
    s1 += __shfl_xor(s1, 32, 64);
    s2 += __shfl_xor(s2, 16, 64);
    s2 += __shfl_xor(s2, 32, 64);
    if (q == 0) {
      red1[w * 32 + ct * 16 + cl] = s1;
      red2[w * 32 + ct * 16 + cl] = s2;
    }
  }
  __syncthreads();
  if (tid < 32) {
    const float s1 = red1[tid] + red1[32 + tid] + red1[64 + tid] + red1[96 + tid];
    const float s2 = red2[tid] + red2[32 + tid] + red2[64 + tid] + red2[96 + tid];
    const float mu = s1 * (1.f / 256.f);
    const float var = s2 * (1.f / 256.f) - mu * mu;
    muA[tid] = mu;
    rsA[tid] = rsqrtf(var + EPSF);
  }
  __syncthreads();

  float* ob = out + (size_t)b * (CC * TT) + tg0;
#pragma unroll
  for (int rt = 0; rt < 4; ++rt)
#pragma unroll
    for (int reg = 0; reg < 4; ++reg) {
      const int o = w * 64 + rt * 16 + q * 4 + reg;
      const float g = gamma[o], bt = beta[o];
#pragma unroll
      for (int ct = 0; ct < 2; ++ct) {
        const int tl = ct * 16 + cl;
        ob[(size_t)o * TT + tl] = (acc[rt][ct][reg] - muA[tl]) * rsA[tl] * g + bt;
      }
    }
}

// ---------------------------------------------------------------------------
extern "C" void kernel_launch(void* const* d_in, const int* in_sizes, int n_in,
                              void* d_out, int out_size, void* d_ws,
                              size_t ws_size, hipStream_t stream) {
  (void)in_sizes; (void)n_in; (void)out_size; (void)ws_size;
  const float* x = (const float*)d_in[0];
  const float* Wpre = (const float*)d_in[1];
  const float* Wproj = (const float*)d_in[2];
  const float* bproj = (const float*)d_in[3];
  const float* scale = (const float*)d_in[4];
  const float* gamma = (const float*)d_in[5];
  const float* beta = (const float*)d_in[6];
  float* out = (float*)d_out;
  float* ws = (float*)d_ws;

  hipLaunchKernelGGL(k0_pack, dim3(768), dim3(256), 0, stream, Wpre, Wproj, ws);
  hipLaunchKernelGGL(k1_kv, dim3(512), dim3(512), 0, stream, x, ws);
  hipLaunchKernelGGL(k2_reduce_kv, dim3(512), dim3(256), 0, stream, ws);
  hipLaunchKernelGGL(k3a_P, dim3(BB * 256), dim3(256), 0, stream, Wpre, ws);
  hipLaunchKernelGGL(k3b_M, dim3(128), dim3(256), 0, stream, scale, ws);
  hipLaunchKernelGGL(k4_proj_ln, dim3(BB * 128 * 2), dim3(256), 0, stream, x,
                     bproj, scale, gamma, beta, ws, out);
}

// Round 2
// 236.016 us; speedup vs baseline: 1.2195x; 1.2195x over previous
//
#include <hip/hip_runtime.h>
#include <hip/hip_bf16.h>
#include <math.h>

// Problem constants
#define BB 8
#define CC 256
#define TT 8192
#define EPSF 1e-5f

typedef short v8s __attribute__((ext_vector_type(8)));
typedef float v4f __attribute__((ext_vector_type(4)));

#define MFMA(a, b, c) __builtin_amdgcn_mfma_f32_16x16x32_bf16((a), (b), (c), 0, 0, 0)

// MFMA 16x16x32 bf16 fragment conventions (m89/m91 verified):
//   A[m][k]: m = lane&15, k = (lane>>4)*8 + j   (8 contiguous k per lane)
//   B[k][n]: n = lane&15, k = (lane>>4)*8 + j
//   C/D:     col = lane&15, row = (lane>>4)*4 + reg

// Workspace layout (float offsets); total ~37.1 MB
#define OFF_WKV 0               // Wkv bf16 [h][type][64][256]  -> 131072 ushort
#define OFF_WPJ 65536           // Wproj bf16 [256][256]        -> 65536 ushort
#define OFF_UPART 98304         // fp32 [512 blk][4h][64][64]   -> 8388608 floats
#define OFF_ZPART 8486912       // fp32 [512 blk][256]
#define OFF_KV 8617984          // fp32 [b][h][64 d][64 e]
#define OFF_PT 8749056          // Pt bf16 [b][c][256 c2]       -> 524288 ushort
#define OFF_MBF 9011200         // M bf16 [b][o][c]             -> 524288 ushort

__device__ __forceinline__ unsigned short f2bf(float f) {
  __hip_bfloat16 h = __float2bfloat16(f);
  return __builtin_bit_cast(unsigned short, h);
}
__device__ __forceinline__ float bf2f(unsigned short u) {
  return __bfloat162float(__builtin_bit_cast(__hip_bfloat16, u));
}
__device__ __forceinline__ unsigned int pack2(float lo, float hi) {
  return (unsigned int)f2bf(lo) | ((unsigned int)f2bf(hi) << 16);
}

// ---------------------------------------------------------------------------
// k0: pack weights to bf16. rows 0..511: Wkv[h][type][d][c]; rows 512..767: Wproj.
// ---------------------------------------------------------------------------
__global__ void k0_pack(const float* __restrict__ Wpre,
                        const float* __restrict__ Wproj,
                        float* __restrict__ ws) {
  const int r = blockIdx.x;
  const int c = threadIdx.x;
  if (r < 512) {
    const int h = r >> 7, type = (r >> 6) & 1, d = r & 63;
    const int src = h * 192 + 64 + type * 64 + d;
    ((unsigned short*)(ws + OFF_WKV))[r * 256 + c] = f2bf(Wpre[(size_t)src * 256 + c]);
  } else {
    const int rr = r - 512;
    ((unsigned short*)(ws + OFF_WPJ))[rr * 256 + c] = f2bf(Wproj[(size_t)rr * 256 + c]);
  }
}

// ---------------------------------------------------------------------------
// k1: per (b, 128-t chunk), 8 waves; wave = (head h = w>>1, type = w&1: 0=k,1=v).
// Grid = 512 blocks, 2 blocks/CU resident.
// NOTE launch_bounds: on this toolchain the 2nd arg for a 512-thread block
// acts as a VGPR cap of 512/(arg*... ) -> arg=2 gives cap 128 (observed 120
// VGPR, no spill); arg=4 gave cap 64 -> 150 MB/pass scratch spill, 2x SLOWER.
// Keep (512,2).
// ---------------------------------------------------------------------------
__global__ __launch_bounds__(512, 2) void k1_kv(const float* __restrict__ x,
                                                float* __restrict__ ws) {
  // union: xs[64][264] ushort (16896) overlaid by per-head e/v buffers
  // (4 heads x (64x40 ek + 64x40 v) = 20480 ushorts = 40 KiB)
  __shared__ unsigned short lds[20480];

  const int tid = threadIdx.x;
  const int w = tid >> 6, lane = tid & 63, q = lane >> 4, cl = lane & 15;
  const int h = w >> 1, type = w & 1;
  const int bi = blockIdx.x;
  const int b = bi >> 6, chunk = bi & 63;
  const int t0 = chunk * 128;
  const float* xb = x + (size_t)b * (CC * TT);
  const unsigned short* wkv =
      (const unsigned short*)(ws + OFF_WKV) + (size_t)((h * 2 + type) * 64) * 256;
  unsigned short* ekb = &lds[h * 5120];         // ek[64][40]
  unsigned short* vbb = &lds[h * 5120 + 2560];  // v [64][40]

  v4f Uacc[2][4];
#pragma unroll
  for (int i = 0; i < 2; ++i)
#pragma unroll
    for (int j = 0; j < 4; ++j) Uacc[i][j] = (v4f){0.f, 0.f, 0.f, 0.f};
  float zacc[4][4];
#pragma unroll
  for (int i = 0; i < 4; ++i)
#pragma unroll
    for (int j = 0; j < 4; ++j) zacc[i][j] = 0.f;

  // staging mapping: thread -> channel pair (c0, c0+1), t-quarter th (16 t)
  const int c0 = (tid & 127) * 2;
  const int th = tid >> 7;  // 0..3
  unsigned int* l32 = (unsigned int*)lds;

  for (int sub = 0; sub < 2; ++sub) {
    const int ts = t0 + sub * 64;
    // ---- stage xs[t][c] (bf16, pitch 264); packed u32 writes: lanes write
    // 4B consecutive -> conflict-free ----
    {
      const float* xpA = xb + (size_t)c0 * TT + ts + th * 16;
      const float* xpB = xpA + TT;
      const int cw = c0 >> 1;
#pragma unroll
      for (int k = 0; k < 4; ++k) {
        const float4 va = reinterpret_cast<const float4*>(xpA)[k];
        const float4 vb = reinterpret_cast<const float4*>(xpB)[k];
        const int tb = th * 16 + k * 4;
        l32[(tb + 0) * 132 + cw] = pack2(va.x, vb.x);
        l32[(tb + 1) * 132 + cw] = pack2(va.y, vb.y);
        l32[(tb + 2) * 132 + cw] = pack2(va.z, vb.z);
        l32[(tb + 3) * 132 + cw] = pack2(va.w, vb.w);
      }
    }
    __syncthreads();

    // ---- phase A: rows = this wave's 64 k- or v-rows, cols = 64 t ----
    v4f acc[4][4];
#pragma unroll
    for (int i = 0; i < 4; ++i)
#pragma unroll
      for (int j = 0; j < 4; ++j) acc[i][j] = (v4f){0.f, 0.f, 0.f, 0.f};
#pragma unroll
    for (int ks = 0; ks < 8; ++ks) {
      v8s af[4], bfu[4];
#pragma unroll
      for (int rt = 0; rt < 4; ++rt)
        af[rt] = *(const v8s*)(wkv + (size_t)(rt * 16 + cl) * 256 + ks * 32 + q * 8);
#pragma unroll
      for (int ct = 0; ct < 4; ++ct)
        bfu[ct] = *(const v8s*)&lds[(ct * 16 + cl) * 264 + ks * 32 + q * 8];
#pragma unroll
      for (int rt = 0; rt < 4; ++rt)
#pragma unroll
        for (int ct = 0; ct < 4; ++ct)
          acc[rt][ct] = MFMA(af[rt], bfu[ct], acc[rt][ct]);
    }
    __syncthreads();  // all waves done with xs; e/v buffers overlay it

    // ---- phase B: two 32-t halves through LDS (pitch 40: 2-way max) ----
#pragma unroll
    for (int hp = 0; hp < 2; ++hp) {
      if (type == 0) {
#pragma unroll
        for (int rt = 0; rt < 4; ++rt)
#pragma unroll
          for (int cc = 0; cc < 2; ++cc) {
            const int ct = hp * 2 + cc;
#pragma unroll
            for (int reg = 0; reg < 4; ++reg) {
              const float e = __expf(acc[rt][ct][reg]);
              zacc[rt][reg] += e;
              ekb[(rt * 16 + q * 4 + reg) * 40 + cc * 16 + cl] = f2bf(e);
            }
          }
      } else {
#pragma unroll
        for (int rt = 0; rt < 4; ++rt)
#pragma unroll
          for (int cc = 0; cc < 2; ++cc) {
            const int ct = hp * 2 + cc;
#pragma unroll
            for (int reg = 0; reg < 4; ++reg)
              vbb[(rt * 16 + q * 4 + reg) * 40 + cc * 16 + cl] =
                  f2bf(acc[rt][ct][reg]);
          }
      }
      __syncthreads();  // head's wave pair exchanges e/v
      {
        const int du0 = type * 32;  // k-wave: U rows 0..31, v-wave: 32..63
        v8s afu[2], bfu[4];
#pragma unroll
        for (int ur = 0; ur < 2; ++ur)
          afu[ur] = *(const v8s*)&ekb[(du0 + ur * 16 + cl) * 40 + q * 8];
#pragma unroll
        for (int uc = 0; uc < 4; ++uc)
          bfu[uc] = *(const v8s*)&vbb[(uc * 16 + cl) * 40 + q * 8];
#pragma unroll
        for (int ur = 0; ur < 2; ++ur)
#pragma unroll
          for (int uc = 0; uc < 4; ++uc)
            Uacc[ur][uc] = MFMA(afu[ur], bfu[uc], Uacc[ur][uc]);
      }
      __syncthreads();  // half-1 / next sub will overwrite buffers
    }
  }

  // ---- Z: butterfly over the 16 col-lanes, store from cl==0 ----
  if (type == 0) {
#pragma unroll
    for (int m = 1; m < 16; m <<= 1)
#pragma unroll
      for (int rt = 0; rt < 4; ++rt)
#pragma unroll
        for (int reg = 0; reg < 4; ++reg)
          zacc[rt][reg] += __shfl_xor(zacc[rt][reg], m, 64);
    if (cl == 0) {
      for (int rt = 0; rt < 4; ++rt)
        for (int reg = 0; reg < 4; ++reg)
          ws[OFF_ZPART + (size_t)bi * 256 + h * 64 + rt * 16 + q * 4 + reg] =
              zacc[rt][reg];
    }
  }
  // ---- U partial store ----
  float* Up = ws + OFF_UPART + (size_t)bi * 16384 + h * 4096;
#pragma unroll
  for (int ur = 0; ur < 2; ++ur)
#pragma unroll
    for (int uc = 0; uc < 4; ++uc)
#pragma unroll
      for (int reg = 0; reg < 4; ++reg)
        Up[(type * 32 + ur * 16 + q * 4 + reg) * 64 + uc * 16 + cl] =
            Uacc[ur][uc][reg];
}

// ---------------------------------------------------------------------------
// k2: reduce 64 partial blocks per batch; kv = U / Z[d].
// ---------------------------------------------------------------------------
__global__ void k2_reduce_kv(float* __restrict__ ws) {
  const int bi = blockIdx.x;  // 0..511
  const int bh = bi >> 4, j = bi & 15;
  const int b = bh >> 2, h = bh & 3;
  const int tid = threadIdx.x;

  __shared__ float zinv[64];
  if (tid < 64) {
    float z = 0.f;
    for (int cb = 0; cb < 64; ++cb)
      z += ws[OFF_ZPART + (size_t)(b * 64 + cb) * 256 + h * 64 + tid];
    zinv[tid] = 1.0f / z;
  }
  __syncthreads();

  const int idx = j * 256 + tid;  // 0..4095 in (b,h)
  const int d = idx >> 6;
  float s = 0.f;
  for (int cb = 0; cb < 64; ++cb)
    s += ws[OFF_UPART + (size_t)(b * 64 + cb) * 16384 + h * 4096 + idx];
  ws[OFF_KV + (size_t)(b * 4 + h) * 4096 + idx] = s * zinv[d];
}

// ---------------------------------------------------------------------------
// k3a: P^T[b][c][h*64+e] = sum_d kv[b,h,d,e] * Wq[h*192+d][c]  (bf16, transposed
// so k3b's B-frags are contiguous along c2)
// ---------------------------------------------------------------------------
__global__ void k3a_P(const float* __restrict__ Wpre, float* __restrict__ ws) {
  const int bi = blockIdx.x;  // b*256 + he
  const int b = bi >> 8, he = bi & 255;
  const int h = he >> 6, e = he & 63;
  const int c = threadIdx.x;
  const float* kvp = ws + OFF_KV + (size_t)(b * 4 + h) * 4096;
  float acc = 0.f;
#pragma unroll 8
  for (int d = 0; d < 64; ++d)
    acc += kvp[d * 64 + e] * Wpre[(size_t)(h * 192 + d) * 256 + c];
  ((unsigned short*)(ws + OFF_PT))[(size_t)b * 65536 + (size_t)c * 256 + he] =
      f2bf(acc);
}

// ---------------------------------------------------------------------------
// k3b: M[b][o][c] = scale * (Wproj @ P)  via MFMA; grid = 8b x 4 cg x 4 rg.
// ---------------------------------------------------------------------------
__global__ __launch_bounds__(256, 2) void k3b_M(const float* __restrict__ scale,
                                                float* __restrict__ ws) {
  const int bi = blockIdx.x;
  const int b = bi >> 4, cg = (bi >> 2) & 3, rg = bi & 3;
  const int tid = threadIdx.x, w = tid >> 6, lane = tid & 63, q = lane >> 4,
            cl = lane & 15;
  const unsigned short* wpj = (const unsigned short*)(ws + OFF_WPJ);
  const unsigned short* pt =
      (const unsigned short*)(ws + OFF_PT) + (size_t)b * 65536;
  v4f acc[4];
#pragma unroll
  for (int j = 0; j < 4; ++j) acc[j] = (v4f){0.f, 0.f, 0.f, 0.f};
#pragma unroll
  for (int ks = 0; ks < 8; ++ks) {
    const v8s af = *(const v8s*)(wpj + (size_t)(rg * 64 + w * 16 + cl) * 256 +
                                 ks * 32 + q * 8);
    v8s bfu[4];
#pragma unroll
    for (int ct = 0; ct < 4; ++ct)
      bfu[ct] = *(const v8s*)(pt + (size_t)(cg * 64 + ct * 16 + cl) * 256 +
                              ks * 32 + q * 8);
#pragma unroll
    for (int ct = 0; ct < 4; ++ct) acc[ct] = MFMA(af, bfu[ct], acc[ct]);
  }
  const float s = scale[0];
  unsigned short* mbf = (unsigned short*)(ws + OFF_MBF);
#pragma unroll
  for (int ct = 0; ct < 4; ++ct)
#pragma unroll
    for (int reg = 0; reg < 4; ++reg) {
      const int o = rg * 64 + w * 16 + q * 4 + reg;
      const int c = cg * 64 + ct * 16 + cl;
      mbf[((size_t)b * 256 + o) * 256 + c] = f2bf(s * acc[ct][reg]);
    }
}

// ---------------------------------------------------------------------------
// k4: out = LN_C( M@x + scale*b_proj + x ) * gamma + beta, MFMA + fused LN.
// Grid: 8b x 256 chunks of 32 t; 4 waves, wave w = rows w*64..w*64+63.
// launch_bounds(256,2): cap 256 VGPR -> no spill risk; if compiler lands
// <=128 we still get 4 blocks/CU naturally.
// ---------------------------------------------------------------------------
__global__ __launch_bounds__(256, 2) void k4_proj_ln(
    const float* __restrict__ x, const float* __restrict__ bproj,
    const float* __restrict__ scale, const float* __restrict__ gamma,
    const float* __restrict__ beta, const float* __restrict__ ws,
    float* __restrict__ out) {
  __shared__ unsigned short xs[32 * 264];
  __shared__ float red1[128], red2[128], muA[32], rsA[32];
  const int bi = blockIdx.x, b = bi >> 8, tc = bi & 255;
  const int tg0 = tc * 32;
  const int tid = threadIdx.x, w = tid >> 6, lane = tid & 63, q = lane >> 4,
            cl = lane & 15;
  const float* xb = x + (size_t)b * (CC * TT);

  // stage x[c][tg0..+32) -> xs[t][c] bf16, packed u32 channel-pair writes
  {
    const int c0 = (tid & 127) * 2;
    const int th = tid >> 7;  // 0..1
    const float* xpA = xb + (size_t)c0 * TT + tg0 + th * 16;
    const float* xpB = xpA + TT;
    unsigned int* x32 = (unsigned int*)xs;
    const int cw = c0 >> 1;
#pragma unroll
    for (int k = 0; k < 4; ++k) {
      const float4 va = reinterpret_cast<const float4*>(xpA)[k];
      const float4 vb = reinterpret_cast<const float4*>(xpB)[k];
      const int tb = th * 16 + k * 4;
      x32[(tb + 0) * 132 + cw] = pack2(va.x, vb.x);
      x32[(tb + 1) * 132 + cw] = pack2(va.y, vb.y);
      x32[(tb + 2) * 132 + cw] = pack2(va.z, vb.z);
      x32[(tb + 3) * 132 + cw] = pack2(va.w, vb.w);
    }
  }
  __syncthreads();

  const unsigned short* mbf =
      (const unsigned short*)(ws + OFF_MBF) + (size_t)b * 65536;
  v4f acc[4][2];
#pragma unroll
  for (int i = 0; i < 4; ++i)
#pragma unroll
    for (int j = 0; j < 2; ++j) acc[i][j] = (v4f){0.f, 0.f, 0.f, 0.f};
#pragma unroll
  for (int ks = 0; ks < 8; ++ks) {
    v8s af[4], bfu[2];
#pragma unroll
    for (int rt = 0; rt < 4; ++rt)
      af[rt] = *(const v8s*)(mbf + (size_t)(w * 64 + rt * 16 + cl) * 256 +
                             ks * 32 + q * 8);
#pragma unroll
    for (int ct = 0; ct < 2; ++ct)
      bfu[ct] = *(const v8s*)&xs[(ct * 16 + cl) * 264 + ks * 32 + q * 8];
#pragma unroll
    for (int rt = 0; rt < 4; ++rt)
#pragma unroll
      for (int ct = 0; ct < 2; ++ct)
        acc[rt][ct] = MFMA(af[rt], bfu[ct], acc[rt][ct]);
  }

  // y = ctx_proj + scale*b_proj + residual (residual from bf16 xs)
  const float s = scale[0];
#pragma unroll
  for (int rt = 0; rt < 4; ++rt)
#pragma unroll
    for (int reg = 0; reg < 4; ++reg) {
      const int o = w * 64 + rt * 16 + q * 4 + reg;
      const float sb = s * bproj[o];
#pragma unroll
      for (int ct = 0; ct < 2; ++ct) {
        const int tl = ct * 16 + cl;
        acc[rt][ct][reg] += sb + bf2f(xs[tl * 264 + o]);
      }
    }

  // LN sums over C: per-lane 16 rows -> butterfly over q -> cross-wave LDS
#pragma unroll
  for (int ct = 0; ct < 2; ++ct) {
    float s1 = 0.f, s2 = 0.f;
#pragma unroll
    for (int rt = 0; rt < 4; ++rt)
#pragma unroll
      for (int reg = 0; reg < 4; ++reg) {
        const float v = acc[rt][ct][reg];
        s1 += v;
        s2 += v * v;
      }
    s1 += __shfl_xor(s1, 16, 64);
    s1 += __shfl_xor(s1, 32, 64);
    s2 += __shfl_xor(s2, 16, 64);
    s2 += __shfl_xor(s2, 32, 64);
    if (q == 0) {
      red1[w * 32 + ct * 16 + cl] = s1;
      red2[w * 32 + ct * 16 + cl] = s2;
    }
  }
  __syncthreads();
  if (tid < 32) {
    const float s1 = red1[tid] + red1[32 + tid] + red1[64 + tid] + red1[96 + tid];
    const float s2 = red2[tid] + red2[32 + tid] + red2[64 + tid] + red2[96 + tid];
    const float mu = s1 * (1.f / 256.f);
    const float var = s2 * (1.f / 256.f) - mu * mu;
    muA[tid] = mu;
    rsA[tid] = rsqrtf(var + EPSF);
  }
  __syncthreads();

  float* ob = out + (size_t)b * (CC * TT) + tg0;
#pragma unroll
  for (int rt = 0; rt < 4; ++rt)
#pragma unroll
    for (int reg = 0; reg < 4; ++reg) {
      const int o = w * 64 + rt * 16 + q * 4 + reg;
      const float g = gamma[o], bt = beta[o];
#pragma unroll
      for (int ct = 0; ct < 2; ++ct) {
        const int tl = ct * 16 + cl;
        ob[(size_t)o * TT + tl] = (acc[rt][ct][reg] - muA[tl]) * rsA[tl] * g + bt;
      }
    }
}

// ---------------------------------------------------------------------------
extern "C" void kernel_launch(void* const* d_in, const int* in_sizes, int n_in,
                              void* d_out, int out_size, void* d_ws,
                              size_t ws_size, hipStream_t stream) {
  (void)in_sizes; (void)n_in; (void)out_size; (void)ws_size;
  const float* x = (const float*)d_in[0];
  const float* Wpre = (const float*)d_in[1];
  const float* Wproj = (const float*)d_in[2];
  const float* bproj = (const float*)d_in[3];
  const float* scale = (const float*)d_in[4];
  const float* gamma = (const float*)d_in[5];
  const float* beta = (const float*)d_in[6];
  float* out = (float*)d_out;
  float* ws = (float*)d_ws;

  hipLaunchKernelGGL(k0_pack, dim3(768), dim3(256), 0, stream, Wpre, Wproj, ws);
  hipLaunchKernelGGL(k1_kv, dim3(512), dim3(512), 0, stream, x, ws);
  hipLaunchKernelGGL(k2_reduce_kv, dim3(512), dim3(256), 0, stream, ws);
  hipLaunchKernelGGL(k3a_P, dim3(BB * 256), dim3(256), 0, stream, Wpre, ws);
  hipLaunchKernelGGL(k3b_M, dim3(128), dim3(256), 0, stream, scale, ws);
  hipLaunchKernelGGL(k4_proj_ln, dim3(BB * 128 * 2), dim3(256), 0, stream, x,
                     bproj, scale, gamma, beta, ws, out);
}